// Round 6
// baseline (191.950 us; speedup 1.0000x reference)
//
#include <hip/hip_runtime.h>
#include <hip/hip_bf16.h>
#include <math.h>

#define NP 256
#define DD 65536

// ws float offsets
#define WS_SQ    65536          // 256
#define WS_KSUM  (65536 + 256)  // 256
#define WS_SIG   66048          // [0]=sigma [1]=1/(2s^2) [2]=1/s^2
// byte offsets
#define XBF_BYTE_OFF   264224u          // gram frags (i,k=d): 33,554,432 B
#define XBTF_BYTE_OFF  33818656u        // der B frags (d,k=i): 33,554,432 B
#define KBF_BYTE_OFF   67373088u        // der A frags (j,k=i): 131,072 B
#define PART_BYTE_OFF  67504160u        // gram K-partials [64][256][256] f32: 16,777,216 B
#define WS_NEED_MID    67504160u
#define WS_NEED_FULL   84281376u

typedef __attribute__((ext_vector_type(8))) short bf16x8;
typedef __attribute__((ext_vector_type(16))) float f32x16;

static __device__ __forceinline__ unsigned short f2bf(float f) {
    __hip_bfloat16 h = __float2bfloat16(f);
    return *reinterpret_cast<unsigned short*>(&h);
}

// ---------------- cast: X fp32 -> fragment-major bf16 tensors ----------------
// Fragment chunk = 32 rows x 16 k: lane (hl=lane>>5, lr=lane&31) holds
// row (base+lr), elements k = hl*8 + 0..7  ->  1 KB contiguous per chunk.
// XbF  chunk index = (i>>5)*4096 + (d>>4)   (gram: contraction over d)
// XbTF chunk index = (d>>5)*16   + (i>>4)   (der : contraction over i)
__global__ __launch_bounds__(256) void cast_kernel(const float* __restrict__ X,
                                                   unsigned short* __restrict__ XbF,
                                                   unsigned short* __restrict__ XbTF) {
    __shared__ __align__(16) unsigned short tile[64][64];   // XOR-swizzled columns
    const int i0 = blockIdx.y * 64, d0 = blockIdx.x * 64;
    const int t = threadIdx.x;
    {
        const int il = t >> 2, dl = (t & 3) * 16;
        const int swz = (il & 7) << 3;
        const float4* src = (const float4*)&X[(size_t)(i0 + il) * DD + d0 + dl];
#pragma unroll
        for (int q = 0; q < 4; q++) {
            float4 v = src[q];
            ushort4 b;
            b.x = f2bf(v.x); b.y = f2bf(v.y); b.z = f2bf(v.z); b.w = f2bf(v.w);
            *(ushort4*)&tile[il][(dl + q * 4) ^ swz] = b;
        }
    }
    __syncthreads();
    const int lane = t & 63, w = t >> 6;
    const int hl = lane >> 5, lr = lane & 31;
#pragma unroll
    for (int cc = 0; cc < 2; cc++) {
        int c = w * 2 + cc;
        int rb_l = c >> 2, k16_l = c & 3;
        int r = rb_l * 32 + lr;
        int c0 = (k16_l * 16 + hl * 8) ^ ((lr & 7) << 3);
        bf16x8 v = *(const bf16x8*)&tile[r][c0];
        int rb_g = (i0 >> 5) + rb_l, k16_g = (d0 >> 4) + k16_l;
        *(bf16x8*)&XbF[(size_t)(rb_g * 4096 + k16_g) * 512 + lane * 8] = v;
    }
#pragma unroll
    for (int cc = 0; cc < 2; cc++) {
        int c = w * 2 + cc;
        int db_l = c >> 2, i16_l = c & 3;
        union { unsigned short u[8]; bf16x8 v; } vals;
#pragma unroll
        for (int e = 0; e < 8; e++) {
            int row = i16_l * 16 + hl * 8 + e;
            int col = (db_l * 32 + lr) ^ ((row & 7) << 3);
            vals.u[e] = tile[row][col];
        }
        int db_g = (d0 >> 5) + db_l, i16_g = (i0 >> 4) + i16_l;
        *(bf16x8*)&XbTF[(size_t)(db_g * 16 + i16_g) * 512 + lane * 8] = vals.v;
    }
}

// ---------------- Gram partials v3: 4x4 register blocking ----------------
// grid (64): ks = K-split. 256 thr = 4 waves (wy=w>>1, wx=w&1), each wave a
// 128x128 output tile (acc[4][4] of 32x32), full 256x256 per block.
// Per ksi: 8 loads (8 KB) feed 16 MFMAs -> 0.5 KB/MFMA operand traffic.
__global__ __launch_bounds__(256, 1) void gram_mfma_part(const unsigned short* __restrict__ XbF,
                                                         float* __restrict__ P) {
    const int t = threadIdx.x;
    const int lane = t & 63, w = t >> 6;
    const int wy = w >> 1, wx = w & 1;
    const int k16_0 = blockIdx.x * 64;

    f32x16 acc[4][4] = {};
    const unsigned short* pA[4];
    const unsigned short* pB[4];
#pragma unroll
    for (int s = 0; s < 4; s++)
        pA[s] = &XbF[(size_t)((wy * 4 + s) * 4096 + k16_0) * 512 + lane * 8];
#pragma unroll
    for (int u = 0; u < 4; u++)
        pB[u] = &XbF[(size_t)((wx * 4 + u) * 4096 + k16_0) * 512 + lane * 8];

    for (int ksi = 0; ksi < 64; ksi++) {
        bf16x8 a[4], b[4];
#pragma unroll
        for (int s = 0; s < 4; s++) a[s] = *(const bf16x8*)(pA[s] + ksi * 512);
#pragma unroll
        for (int u = 0; u < 4; u++) b[u] = *(const bf16x8*)(pB[u] + ksi * 512);
#pragma unroll
        for (int s = 0; s < 4; s++)
#pragma unroll
            for (int u = 0; u < 4; u++)
                acc[s][u] = __builtin_amdgcn_mfma_f32_32x32x16_bf16(a[s], b[u], acc[s][u], 0, 0, 0);
    }
    const int hl = lane >> 5, lr = lane & 31;
    float* Pz = P + (size_t)blockIdx.x * 65536;
#pragma unroll
    for (int s = 0; s < 4; s++) {
        int ibase = wy * 128 + s * 32 + 4 * hl;
#pragma unroll
        for (int u = 0; u < 4; u++) {
            int jc = wx * 128 + u * 32 + lr;
#pragma unroll
            for (int r = 0; r < 16; r++) {
                int ir = ibase + (r & 3) + 8 * (r >> 2);
                Pz[ir * 256 + jc] = acc[s][u][r];
            }
        }
    }
}

// ---------------- reduce 64 K-partials -> G ----------------
__global__ __launch_bounds__(256) void gram_reduce(const float* __restrict__ P,
                                                   float* __restrict__ G) {
    const int e4 = blockIdx.x * 256 + threadIdx.x;   // 16384 float4 slots
    const float4* P4 = (const float4*)P;
    float4 s = {0.f, 0.f, 0.f, 0.f};
#pragma unroll 8
    for (int z = 0; z < 64; z++) {
        float4 v = P4[(size_t)z * 16384 + e4];
        s.x += v.x; s.y += v.y; s.z += v.z; s.w += v.w;
    }
    ((float4*)G)[e4] = s;
}

// ---------------- single-launch exact median + sigma ----------------
#define MBINS 8192
__global__ __launch_bounds__(1024) void median_sigma_kernel(const float* __restrict__ G,
                                                            const float* __restrict__ EMA,
                                                            float* __restrict__ sq_ws,
                                                            float* __restrict__ sig,
                                                            float* __restrict__ sigma_out) {
    __shared__ float sq_l[256];
    __shared__ float red[32];
    __shared__ float s_mn, s_mx, s_v0, s_v1;
    __shared__ unsigned hist[MBINS];
    __shared__ unsigned scan[1024];
    __shared__ unsigned s_b0, s_b1, s_base0, s_gcnt;
    const int t = threadIdx.x;
    if (t < 256) { float v = G[t * (NP + 1)]; sq_l[t] = v; sq_ws[t] = v; }
    __syncthreads();

    float dv[64];
    float mn = 3.4e38f, mx = -3.4e38f;
    const float4* G4 = (const float4*)G;
#pragma unroll
    for (int q = 0; q < 16; q++) {
        int idx4 = q * 1024 + t;
        float4 g = G4[idx4];
        int i = idx4 >> 6, jb = (idx4 * 4) & 255;
        float si = sq_l[i];
        float d0 = fmaxf(si + sq_l[jb + 0] - 2.f * g.x, 0.f);
        float d1 = fmaxf(si + sq_l[jb + 1] - 2.f * g.y, 0.f);
        float d2 = fmaxf(si + sq_l[jb + 2] - 2.f * g.z, 0.f);
        float d3 = fmaxf(si + sq_l[jb + 3] - 2.f * g.w, 0.f);
        dv[q * 4 + 0] = d0; dv[q * 4 + 1] = d1; dv[q * 4 + 2] = d2; dv[q * 4 + 3] = d3;
        mn = fminf(mn, fminf(fminf(d0, d1), fminf(d2, d3)));
        mx = fmaxf(mx, fmaxf(fmaxf(d0, d1), fmaxf(d2, d3)));
    }
    for (int off = 32; off; off >>= 1) {
        mn = fminf(mn, __shfl_down(mn, off));
        mx = fmaxf(mx, __shfl_down(mx, off));
    }
    if (!(t & 63)) { red[t >> 6] = mn; red[16 + (t >> 6)] = mx; }
    for (int i = t; i < MBINS; i += 1024) hist[i] = 0;
    if (t == 0) s_gcnt = 0;
    __syncthreads();
    if (t == 0) {
        float a = red[0], b = red[16];
        for (int i = 1; i < 16; i++) { a = fminf(a, red[i]); b = fmaxf(b, red[16 + i]); }
        s_mn = a; s_mx = b;
    }
    __syncthreads();
    const float mn0 = s_mn;
    const float scale = (s_mx > mn0) ? (float)MBINS * 0.9999f / (s_mx - mn0) : 0.f;
#pragma unroll
    for (int q = 0; q < 64; q++) {
        int b = min((int)((dv[q] - mn0) * scale), MBINS - 1);
        atomicAdd(&hist[b], 1u);
    }
    __syncthreads();
    unsigned part = 0;
#pragma unroll
    for (int i = 0; i < 8; i++) part += hist[t * 8 + i];
    scan[t] = part;
    __syncthreads();
    for (int off = 1; off < 1024; off <<= 1) {
        unsigned v = (t >= off) ? scan[t - off] : 0u;
        __syncthreads();
        scan[t] += v;
        __syncthreads();
    }
    unsigned run = scan[t] - part;
#pragma unroll
    for (int i = 0; i < 8; i++) {
        unsigned h = hist[t * 8 + i];
        if (h) {
            if (run <= 32767u && 32767u < run + h) { s_b0 = t * 8 + i; s_base0 = run; }
            if (run <= 32768u && 32768u < run + h) { s_b1 = t * 8 + i; }
        }
        run += h;
    }
    __syncthreads();
    const unsigned b0 = s_b0, b1 = s_b1, base0 = s_base0;
    __syncthreads();
    float* gbuf = (float*)hist;
#pragma unroll
    for (int q = 0; q < 64; q++) {
        unsigned b = (unsigned)min((int)((dv[q] - mn0) * scale), MBINS - 1);
        if (b >= b0 && b <= b1) {
            unsigned p = atomicAdd(&s_gcnt, 1u);
            if (p < (unsigned)MBINS) gbuf[p] = dv[q];
        }
    }
    __syncthreads();
    const unsigned m = min(s_gcnt, (unsigned)MBINS);
    for (unsigned c = t; c < m; c += 1024) {
        float e = gbuf[c];
        unsigned lt = 0, eq = 0;
        for (unsigned i2 = 0; i2 < m; i2++) {
            float o = gbuf[i2];
            lt += (o < e); eq += (o == e);
        }
        unsigned rlo = base0 + lt, rhi = rlo + eq - 1u;
        if (rlo <= 32767u && 32767u <= rhi) s_v0 = e;
        if (rlo <= 32768u && 32768u <= rhi) s_v1 = e;
    }
    __syncthreads();
    if (t == 0) {
        float med = 0.5f * (s_v0 + s_v1);
        float hh = med / (2.0f * logf((float)(NP + 1)));
        float s = sqrtf(hh);
        float e1 = EMA[1], e0 = EMA[0];
        s = e1 * s + (1.f - e1) * e0;
        sig[0] = s;
        sig[1] = 1.f / (2.f * s * s);
        sig[2] = 1.f / (s * s);
        *sigma_out = s;
    }
}

// ---------------- k from G,sq; kout fp32 + kbF (A-fragment layout) + ksum ----------------
__global__ __launch_bounds__(256) void kexp_kernel(const float* __restrict__ G,
                                                   const float* __restrict__ sq,
                                                   const float* __restrict__ sig,
                                                   float* __restrict__ kout,
                                                   unsigned short* __restrict__ kbF,
                                                   float* __restrict__ ksum) {
    int j = blockIdx.x, i = threadIdx.x;
    float d = fmaxf(sq[i] + sq[j] - 2.f * G[j * NP + i], 0.f);
    float kv = expf(-d * sig[1]);
    kout[j * NP + i] = kv;
    if (kbF) {
        int chunk = (j >> 5) * 16 + (i >> 4);
        int lanee = ((i >> 3) & 1) * 32 + (j & 31);
        kbF[chunk * 512 + lanee * 8 + (i & 7)] = f2bf(kv);
    }
    float s = kv;
    for (int off = 32; off > 0; off >>= 1) s += __shfl_down(s, off);
    __shared__ float wsum[4];
    int lane = i & 63, w = i >> 6;
    if (lane == 0) wsum[w] = s;
    __syncthreads();
    if (i == 0) ksum[j] = wsum[0] + wsum[1] + wsum[2] + wsum[3];
}

// ---------------- der v3: 4x4 register blocking; fused epilogue (x from fp32 X) ----------------
// grid (256): 256-d-col blocks. 256 thr = 4 waves (wj=w>>1: 128 j, wd=w&1: 128 d),
// wave = 128j x 128d (acc[4][4] of 32x32). 16 i16-steps; 8 loads / 16 MFMAs per step.
__global__ __launch_bounds__(256, 1) void der_mfma(const unsigned short* __restrict__ kbF,
                                                   const unsigned short* __restrict__ XbTF,
                                                   const float* __restrict__ X,
                                                   const float* __restrict__ ksum,
                                                   const float* __restrict__ sig,
                                                   float* __restrict__ der) {
    const int t = threadIdx.x;
    const int lane = t & 63, w = t >> 6;
    const int wj = w >> 1, wd = w & 1;
    const int d0 = blockIdx.x * 256;

    f32x16 acc[4][4] = {};
    const unsigned short* pA[4];
    const unsigned short* pB[4];
#pragma unroll
    for (int s = 0; s < 4; s++)
        pA[s] = &kbF[(size_t)((wj * 4 + s) * 16) * 512 + lane * 8];
#pragma unroll
    for (int u = 0; u < 4; u++)
        pB[u] = &XbTF[(size_t)(((d0 >> 5) + wd * 4 + u) * 16) * 512 + lane * 8];

    for (int i16 = 0; i16 < 16; i16++) {
        bf16x8 a[4], b[4];
#pragma unroll
        for (int s = 0; s < 4; s++) a[s] = *(const bf16x8*)(pA[s] + i16 * 512);
#pragma unroll
        for (int u = 0; u < 4; u++) b[u] = *(const bf16x8*)(pB[u] + i16 * 512);
#pragma unroll
        for (int s = 0; s < 4; s++)
#pragma unroll
            for (int u = 0; u < 4; u++)
                acc[s][u] = __builtin_amdgcn_mfma_f32_32x32x16_bf16(a[s], b[u], acc[s][u], 0, 0, 0);
    }
    const int hl = lane >> 5, lr = lane & 31;
    const float invs2 = sig[2];
#pragma unroll
    for (int u = 0; u < 4; u++) {
        const int dcol = d0 + wd * 128 + u * 32 + lr;
#pragma unroll
        for (int s = 0; s < 4; s++) {
            const int jt = wj * 128 + s * 32;
#pragma unroll
            for (int q = 0; q < 4; q++) {
                int jq = jt + q * 8 + 4 * hl;
                float4 ks4 = *(const float4*)&ksum[jq];
                float x0 = X[(size_t)(jq + 0) * DD + dcol];
                float x1 = X[(size_t)(jq + 1) * DD + dcol];
                float x2 = X[(size_t)(jq + 2) * DD + dcol];
                float x3 = X[(size_t)(jq + 3) * DD + dcol];
                der[(size_t)(jq + 0) * DD + dcol] = (acc[s][u][q * 4 + 0] - ks4.x * x0) * invs2;
                der[(size_t)(jq + 1) * DD + dcol] = (acc[s][u][q * 4 + 1] - ks4.y * x1) * invs2;
                der[(size_t)(jq + 2) * DD + dcol] = (acc[s][u][q * 4 + 2] - ks4.z * x2) * invs2;
                der[(size_t)(jq + 3) * DD + dcol] = (acc[s][u][q * 4 + 3] - ks4.w * x3) * invs2;
            }
        }
    }
}

// ---------------- mid-path gram (atomic version, ws < full) ----------------
__global__ __launch_bounds__(512) void gram_mfma(const unsigned short* __restrict__ XbF,
                                                 float* __restrict__ G) {
    const int t = threadIdx.x;
    const int lane = t & 63, w = t >> 6;
    const int wr = w >> 2, wc = w & 3;
    const int kc0 = blockIdx.x * 64;

    f32x16 acc[4][2] = {};
    const unsigned short* pA[4];
    const unsigned short* pB[2];
#pragma unroll
    for (int s = 0; s < 4; s++)
        pA[s] = &XbF[(size_t)((wr * 4 + s) * 4096 + kc0) * 512 + lane * 8];
#pragma unroll
    for (int u = 0; u < 2; u++)
        pB[u] = &XbF[(size_t)((wc * 2 + u) * 4096 + kc0) * 512 + lane * 8];

#pragma unroll 2
    for (int ks = 0; ks < 64; ks++) {
        bf16x8 a[4], b[2];
#pragma unroll
        for (int s = 0; s < 4; s++) a[s] = *(const bf16x8*)(pA[s] + ks * 512);
#pragma unroll
        for (int u = 0; u < 2; u++) b[u] = *(const bf16x8*)(pB[u] + ks * 512);
#pragma unroll
        for (int s = 0; s < 4; s++)
#pragma unroll
            for (int u = 0; u < 2; u++)
                acc[s][u] = __builtin_amdgcn_mfma_f32_32x32x16_bf16(a[s], b[u], acc[s][u], 0, 0, 0);
    }
    const int hl = lane >> 5, lr = lane & 31;
#pragma unroll
    for (int s = 0; s < 4; s++)
#pragma unroll
        for (int u = 0; u < 2; u++) {
            int jc = wc * 64 + u * 32 + lr;
#pragma unroll
            for (int r = 0; r < 16; r++) {
                int ir = wr * 128 + s * 32 + (r & 3) + 8 * (r >> 2) + 4 * hl;
                atomicAdd(&G[ir * NP + jc], acc[s][u][r]);
            }
        }
}

// ================= fallback fp32 path (ws too small) =================
__global__ __launch_bounds__(256) void gram_kernel(const float* __restrict__ X,
                                                   float* __restrict__ G) {
    __shared__ __align__(16) float As[32][72];
    __shared__ __align__(16) float Bs[32][72];
    const int i0 = blockIdx.x * 64;
    const int j0 = blockIdx.y * 64;
    const int k0 = blockIdx.z * 2048;
    const int t  = threadIdx.x;
    const int tx = t & 15, ty = t >> 4;
    float acc[4][4];
#pragma unroll
    for (int q = 0; q < 4; q++)
#pragma unroll
        for (int r = 0; r < 4; r++) acc[q][r] = 0.f;
    for (int kb = k0; kb < k0 + 2048; kb += 32) {
#pragma unroll
        for (int u = 0; u < 2; u++) {
            int f = t * 2 + u, row = f >> 3, c4 = (f & 7) * 4;
            float4 av = *(const float4*)&X[(size_t)(i0 + row) * DD + kb + c4];
            As[c4 + 0][row] = av.x; As[c4 + 1][row] = av.y;
            As[c4 + 2][row] = av.z; As[c4 + 3][row] = av.w;
            float4 bv = *(const float4*)&X[(size_t)(j0 + row) * DD + kb + c4];
            Bs[c4 + 0][row] = bv.x; Bs[c4 + 1][row] = bv.y;
            Bs[c4 + 2][row] = bv.z; Bs[c4 + 3][row] = bv.w;
        }
        __syncthreads();
#pragma unroll
        for (int kk = 0; kk < 32; kk++) {
            float4 a4 = *(const float4*)&As[kk][ty * 4];
            float4 b4 = *(const float4*)&Bs[kk][tx * 4];
            acc[0][0] += a4.x * b4.x; acc[0][1] += a4.x * b4.y;
            acc[0][2] += a4.x * b4.z; acc[0][3] += a4.x * b4.w;
            acc[1][0] += a4.y * b4.x; acc[1][1] += a4.y * b4.y;
            acc[1][2] += a4.y * b4.z; acc[1][3] += a4.y * b4.w;
            acc[2][0] += a4.z * b4.x; acc[2][1] += a4.z * b4.y;
            acc[2][2] += a4.z * b4.z; acc[2][3] += a4.z * b4.w;
            acc[3][0] += a4.w * b4.x; acc[3][1] += a4.w * b4.y;
            acc[3][2] += a4.w * b4.z; acc[3][3] += a4.w * b4.w;
        }
        __syncthreads();
    }
#pragma unroll
    for (int q = 0; q < 4; q++)
#pragma unroll
        for (int r = 0; r < 4; r++)
            atomicAdd(&G[(size_t)(i0 + ty * 4 + q) * NP + j0 + tx * 4 + r], acc[q][r]);
}

__global__ __launch_bounds__(256) void der_kernel(const float* __restrict__ X,
                                                  const float* __restrict__ kmat,
                                                  const float* __restrict__ ksum,
                                                  const float* __restrict__ sig,
                                                  float* __restrict__ der) {
    const int j0 = blockIdx.y * 32;
    const int d0 = blockIdx.x * 512 + threadIdx.x * 2;
    const float invs2 = sig[2];
    float2 acc[32];
#pragma unroll
    for (int jl = 0; jl < 32; jl++) { acc[jl].x = 0.f; acc[jl].y = 0.f; }
    for (int i = 0; i < NP; i++) {
        float2 xv = *(const float2*)&X[(size_t)i * DD + d0];
        const float4* kr = (const float4*)&kmat[i * NP + j0];
#pragma unroll
        for (int q = 0; q < 8; q++) {
            float4 k4 = kr[q];
            acc[q * 4 + 0].x += k4.x * xv.x; acc[q * 4 + 0].y += k4.x * xv.y;
            acc[q * 4 + 1].x += k4.y * xv.x; acc[q * 4 + 1].y += k4.y * xv.y;
            acc[q * 4 + 2].x += k4.z * xv.x; acc[q * 4 + 2].y += k4.z * xv.y;
            acc[q * 4 + 3].x += k4.w * xv.x; acc[q * 4 + 3].y += k4.w * xv.y;
        }
    }
#pragma unroll
    for (int jl = 0; jl < 32; jl++) {
        int j = j0 + jl;
        float2 xj = *(const float2*)&X[(size_t)j * DD + d0];
        float ks = ksum[j];
        float2 o;
        o.x = (acc[jl].x - ks * xj.x) * invs2;
        o.y = (acc[jl].y - ks * xj.y) * invs2;
        *(float2*)&der[(size_t)j * DD + d0] = o;
    }
}

extern "C" void kernel_launch(void* const* d_in, const int* in_sizes, int n_in,
                              void* d_out, int out_size, void* d_ws, size_t ws_size,
                              hipStream_t stream) {
    const float* X   = (const float*)d_in[0];
    const float* EMA = (const float*)d_in[1];
    float* out = (float*)d_out;
    float* ws  = (float*)d_ws;

    float* G    = ws;
    float* sq   = ws + WS_SQ;
    float* ksum = ws + WS_KSUM;
    float* sig  = ws + WS_SIG;

    float* kout      = out;
    float* der       = out + NP * NP;
    float* sigma_out = out + out_size - 1;

    if (ws_size >= (size_t)WS_NEED_MID) {
        unsigned short* XbF  = (unsigned short*)((char*)d_ws + XBF_BYTE_OFF);
        unsigned short* XbTF = (unsigned short*)((char*)d_ws + XBTF_BYTE_OFF);
        unsigned short* kbF  = (unsigned short*)((char*)d_ws + KBF_BYTE_OFF);

        cast_kernel<<<dim3(1024, 4), 256, 0, stream>>>(X, XbF, XbTF);
        if (ws_size >= (size_t)WS_NEED_FULL) {
            float* P = (float*)((char*)d_ws + PART_BYTE_OFF);
            gram_mfma_part<<<64, 256, 0, stream>>>(XbF, P);
            gram_reduce<<<64, 256, 0, stream>>>(P, G);
        } else {
            hipMemsetAsync(G, 0, (size_t)NP * NP * sizeof(float), stream);
            gram_mfma<<<64, 512, 0, stream>>>(XbF, G);
        }
        median_sigma_kernel<<<1, 1024, 0, stream>>>(G, EMA, sq, sig, sigma_out);
        kexp_kernel<<<NP, NP, 0, stream>>>(G, sq, sig, kout, kbF, ksum);
        der_mfma<<<256, 256, 0, stream>>>(kbF, XbTF, X, ksum, sig, der);
    } else {
        hipMemsetAsync(G, 0, (size_t)NP * NP * sizeof(float), stream);
        gram_kernel<<<dim3(4, 4, 32), 256, 0, stream>>>(X, G);
        median_sigma_kernel<<<1, 1024, 0, stream>>>(G, EMA, sq, sig, sigma_out);
        kexp_kernel<<<NP, NP, 0, stream>>>(G, sq, sig, kout, nullptr, ksum);
        der_kernel<<<dim3(128, 8), 256, 0, stream>>>(X, kout, ksum, sig, der);
    }
}

// Round 7
// 124.903 us; speedup vs baseline: 1.5368x; 1.5368x over previous
//
#include <hip/hip_runtime.h>
#include <hip/hip_bf16.h>
#include <math.h>

#define NP 256
#define DD 65536

// ws float offsets
#define WS_SQ    65536          // 256
#define WS_KSUM  (65536 + 256)  // 256
#define WS_SIG   66048          // [0]=sigma [1]=1/(2s^2) [2]=1/s^2
// byte offsets
#define XBF_BYTE_OFF   264224u          // gram frags (i,k=d): 33,554,432 B
#define XBTF_BYTE_OFF  33818656u        // der B frags (d,k=i): 33,554,432 B
#define KBF_BYTE_OFF   67373088u        // der A frags (j,k=i): 131,072 B
#define PART_BYTE_OFF  67504160u        // gram K-partials [64][256][256] f32: 16,777,216 B
#define WS_NEED_MID    67504160u
#define WS_NEED_FULL   84281376u

typedef __attribute__((ext_vector_type(8))) short bf16x8;
typedef __attribute__((ext_vector_type(16))) float f32x16;

static __device__ __forceinline__ unsigned short f2bf(float f) {
    __hip_bfloat16 h = __float2bfloat16(f);
    return *reinterpret_cast<unsigned short*>(&h);
}
static __device__ __forceinline__ float bf2f(unsigned short u) {
    return __uint_as_float((unsigned)u << 16);
}
// read element (d, i) from XbTF fragment layout
static __device__ __forceinline__ float xtF(const unsigned short* __restrict__ XbTF,
                                            int d, int i) {
    return bf2f(XbTF[((size_t)((d >> 5) * 16 + (i >> 4))) * 512 +
                     (((i >> 3) & 1) * 32 + (d & 31)) * 8 + (i & 7)]);
}

// ---------------- cast: X fp32 -> fragment-major bf16 tensors ----------------
// Fragment chunk = 32 rows x 16 k: lane (hl=lane>>5, lr=lane&31) holds
// row (base+lr), elements k = hl*8 + 0..7  ->  1 KB contiguous per chunk.
// XbF  chunk index = (i>>5)*4096 + (d>>4)   (gram: contraction over d)
// XbTF chunk index = (d>>5)*16   + (i>>4)   (der : contraction over i)
__global__ __launch_bounds__(256) void cast_kernel(const float* __restrict__ X,
                                                   unsigned short* __restrict__ XbF,
                                                   unsigned short* __restrict__ XbTF) {
    __shared__ __align__(16) unsigned short tile[64][64];   // XOR-swizzled columns
    const int i0 = blockIdx.y * 64, d0 = blockIdx.x * 64;
    const int t = threadIdx.x;
    {
        const int il = t >> 2, dl = (t & 3) * 16;
        const int swz = (il & 7) << 3;
        const float4* src = (const float4*)&X[(size_t)(i0 + il) * DD + d0 + dl];
#pragma unroll
        for (int q = 0; q < 4; q++) {
            float4 v = src[q];
            ushort4 b;
            b.x = f2bf(v.x); b.y = f2bf(v.y); b.z = f2bf(v.z); b.w = f2bf(v.w);
            *(ushort4*)&tile[il][(dl + q * 4) ^ swz] = b;
        }
    }
    __syncthreads();
    const int lane = t & 63, w = t >> 6;
    const int hl = lane >> 5, lr = lane & 31;
#pragma unroll
    for (int cc = 0; cc < 2; cc++) {
        int c = w * 2 + cc;
        int rb_l = c >> 2, k16_l = c & 3;
        int r = rb_l * 32 + lr;
        int c0 = (k16_l * 16 + hl * 8) ^ ((lr & 7) << 3);
        bf16x8 v = *(const bf16x8*)&tile[r][c0];
        int rb_g = (i0 >> 5) + rb_l, k16_g = (d0 >> 4) + k16_l;
        *(bf16x8*)&XbF[(size_t)(rb_g * 4096 + k16_g) * 512 + lane * 8] = v;
    }
#pragma unroll
    for (int cc = 0; cc < 2; cc++) {
        int c = w * 2 + cc;
        int db_l = c >> 2, i16_l = c & 3;
        union { unsigned short u[8]; bf16x8 v; } vals;
#pragma unroll
        for (int e = 0; e < 8; e++) {
            int row = i16_l * 16 + hl * 8 + e;
            int col = (db_l * 32 + lr) ^ ((row & 7) << 3);
            vals.u[e] = tile[row][col];
        }
        int db_g = (d0 >> 5) + db_l, i16_g = (i0 >> 4) + i16_l;
        *(bf16x8*)&XbTF[(size_t)(db_g * 16 + i16_g) * 512 + lane * 8] = vals.v;
    }
}

// ---------------- Gram partials v4: acc[2][2], 4 waves, 256 blocks ----------------
// grid (2,2,64): (bx=j-tile, by=i-tile, ks=K-split). 256 thr = 4 waves (wy=w>>1,
// wx=w&1), wave = 64x64 (acc[2][2] of 32x32), block tile 128x128. K-chunk 1024.
// Per ksi: 4 loads (4 KB) feed 4 MFMAs; ~110 arch VGPR -> 4 waves/SIMD capacity.
__global__ __launch_bounds__(256) void gram_mfma_part(const unsigned short* __restrict__ XbF,
                                                      float* __restrict__ P) {
    const int t = threadIdx.x;
    const int lane = t & 63, w = t >> 6;
    const int wy = w >> 1, wx = w & 1;
    const int bx = blockIdx.x, by = blockIdx.y;
    const int k16_0 = blockIdx.z * 64;

    f32x16 acc[2][2] = {};
    const unsigned short* pA[2];
    const unsigned short* pB[2];
#pragma unroll
    for (int s = 0; s < 2; s++)
        pA[s] = &XbF[(size_t)((by * 4 + wy * 2 + s) * 4096 + k16_0) * 512 + lane * 8];
#pragma unroll
    for (int u = 0; u < 2; u++)
        pB[u] = &XbF[(size_t)((bx * 4 + wx * 2 + u) * 4096 + k16_0) * 512 + lane * 8];

#pragma unroll 4
    for (int ksi = 0; ksi < 64; ksi++) {
        bf16x8 a[2], b[2];
#pragma unroll
        for (int s = 0; s < 2; s++) a[s] = *(const bf16x8*)(pA[s] + ksi * 512);
#pragma unroll
        for (int u = 0; u < 2; u++) b[u] = *(const bf16x8*)(pB[u] + ksi * 512);
#pragma unroll
        for (int s = 0; s < 2; s++)
#pragma unroll
            for (int u = 0; u < 2; u++)
                acc[s][u] = __builtin_amdgcn_mfma_f32_32x32x16_bf16(a[s], b[u], acc[s][u], 0, 0, 0);
    }
    const int hl = lane >> 5, lr = lane & 31;
    float* Pz = P + (size_t)blockIdx.z * 65536;
#pragma unroll
    for (int s = 0; s < 2; s++) {
        int ibase = by * 128 + wy * 64 + s * 32 + 4 * hl;
#pragma unroll
        for (int u = 0; u < 2; u++) {
            int jc = bx * 128 + wx * 64 + u * 32 + lr;
#pragma unroll
            for (int r = 0; r < 16; r++) {
                int ir = ibase + (r & 3) + 8 * (r >> 2);
                Pz[ir * 256 + jc] = acc[s][u][r];
            }
        }
    }
}

// ---------------- reduce 64 K-partials -> G ----------------
__global__ __launch_bounds__(256) void gram_reduce(const float* __restrict__ P,
                                                   float* __restrict__ G) {
    const int e4 = blockIdx.x * 256 + threadIdx.x;   // 16384 float4 slots
    const float4* P4 = (const float4*)P;
    float4 s = {0.f, 0.f, 0.f, 0.f};
#pragma unroll 8
    for (int z = 0; z < 64; z++) {
        float4 v = P4[(size_t)z * 16384 + e4];
        s.x += v.x; s.y += v.y; s.z += v.z; s.w += v.w;
    }
    ((float4*)G)[e4] = s;
}

// ---------------- single-launch exact median + sigma ----------------
#define MBINS 8192
__global__ __launch_bounds__(1024) void median_sigma_kernel(const float* __restrict__ G,
                                                            const float* __restrict__ EMA,
                                                            float* __restrict__ sq_ws,
                                                            float* __restrict__ sig,
                                                            float* __restrict__ sigma_out) {
    __shared__ float sq_l[256];
    __shared__ float red[32];
    __shared__ float s_mn, s_mx, s_v0, s_v1;
    __shared__ unsigned hist[MBINS];
    __shared__ unsigned scan[1024];
    __shared__ unsigned s_b0, s_b1, s_base0, s_gcnt;
    const int t = threadIdx.x;
    if (t < 256) { float v = G[t * (NP + 1)]; sq_l[t] = v; sq_ws[t] = v; }
    __syncthreads();

    float dv[64];
    float mn = 3.4e38f, mx = -3.4e38f;
    const float4* G4 = (const float4*)G;
#pragma unroll
    for (int q = 0; q < 16; q++) {
        int idx4 = q * 1024 + t;
        float4 g = G4[idx4];
        int i = idx4 >> 6, jb = (idx4 * 4) & 255;
        float si = sq_l[i];
        float d0 = fmaxf(si + sq_l[jb + 0] - 2.f * g.x, 0.f);
        float d1 = fmaxf(si + sq_l[jb + 1] - 2.f * g.y, 0.f);
        float d2 = fmaxf(si + sq_l[jb + 2] - 2.f * g.z, 0.f);
        float d3 = fmaxf(si + sq_l[jb + 3] - 2.f * g.w, 0.f);
        dv[q * 4 + 0] = d0; dv[q * 4 + 1] = d1; dv[q * 4 + 2] = d2; dv[q * 4 + 3] = d3;
        mn = fminf(mn, fminf(fminf(d0, d1), fminf(d2, d3)));
        mx = fmaxf(mx, fmaxf(fmaxf(d0, d1), fmaxf(d2, d3)));
    }
    for (int off = 32; off; off >>= 1) {
        mn = fminf(mn, __shfl_down(mn, off));
        mx = fmaxf(mx, __shfl_down(mx, off));
    }
    if (!(t & 63)) { red[t >> 6] = mn; red[16 + (t >> 6)] = mx; }
    for (int i = t; i < MBINS; i += 1024) hist[i] = 0;
    if (t == 0) s_gcnt = 0;
    __syncthreads();
    if (t == 0) {
        float a = red[0], b = red[16];
        for (int i = 1; i < 16; i++) { a = fminf(a, red[i]); b = fmaxf(b, red[16 + i]); }
        s_mn = a; s_mx = b;
    }
    __syncthreads();
    const float mn0 = s_mn;
    const float scale = (s_mx > mn0) ? (float)MBINS * 0.9999f / (s_mx - mn0) : 0.f;
#pragma unroll
    for (int q = 0; q < 64; q++) {
        int b = min((int)((dv[q] - mn0) * scale), MBINS - 1);
        atomicAdd(&hist[b], 1u);
    }
    __syncthreads();
    unsigned part = 0;
#pragma unroll
    for (int i = 0; i < 8; i++) part += hist[t * 8 + i];
    scan[t] = part;
    __syncthreads();
    for (int off = 1; off < 1024; off <<= 1) {
        unsigned v = (t >= off) ? scan[t - off] : 0u;
        __syncthreads();
        scan[t] += v;
        __syncthreads();
    }
    unsigned run = scan[t] - part;
#pragma unroll
    for (int i = 0; i < 8; i++) {
        unsigned h = hist[t * 8 + i];
        if (h) {
            if (run <= 32767u && 32767u < run + h) { s_b0 = t * 8 + i; s_base0 = run; }
            if (run <= 32768u && 32768u < run + h) { s_b1 = t * 8 + i; }
        }
        run += h;
    }
    __syncthreads();
    const unsigned b0 = s_b0, b1 = s_b1, base0 = s_base0;
    __syncthreads();
    float* gbuf = (float*)hist;
#pragma unroll
    for (int q = 0; q < 64; q++) {
        unsigned b = (unsigned)min((int)((dv[q] - mn0) * scale), MBINS - 1);
        if (b >= b0 && b <= b1) {
            unsigned p = atomicAdd(&s_gcnt, 1u);
            if (p < (unsigned)MBINS) gbuf[p] = dv[q];
        }
    }
    __syncthreads();
    const unsigned m = min(s_gcnt, (unsigned)MBINS);
    for (unsigned c = t; c < m; c += 1024) {
        float e = gbuf[c];
        unsigned lt = 0, eq = 0;
        for (unsigned i2 = 0; i2 < m; i2++) {
            float o = gbuf[i2];
            lt += (o < e); eq += (o == e);
        }
        unsigned rlo = base0 + lt, rhi = rlo + eq - 1u;
        if (rlo <= 32767u && 32767u <= rhi) s_v0 = e;
        if (rlo <= 32768u && 32768u <= rhi) s_v1 = e;
    }
    __syncthreads();
    if (t == 0) {
        float med = 0.5f * (s_v0 + s_v1);
        float hh = med / (2.0f * logf((float)(NP + 1)));
        float s = sqrtf(hh);
        float e1 = EMA[1], e0 = EMA[0];
        s = e1 * s + (1.f - e1) * e0;
        sig[0] = s;
        sig[1] = 1.f / (2.f * s * s);
        sig[2] = 1.f / (s * s);
        *sigma_out = s;
    }
}

// ---------------- k from G,sq; kout fp32 + kbF (A-fragment layout) + ksum ----------------
__global__ __launch_bounds__(256) void kexp_kernel(const float* __restrict__ G,
                                                   const float* __restrict__ sq,
                                                   const float* __restrict__ sig,
                                                   float* __restrict__ kout,
                                                   unsigned short* __restrict__ kbF,
                                                   float* __restrict__ ksum) {
    int j = blockIdx.x, i = threadIdx.x;
    float d = fmaxf(sq[i] + sq[j] - 2.f * G[j * NP + i], 0.f);
    float kv = expf(-d * sig[1]);
    kout[j * NP + i] = kv;
    if (kbF) {
        int chunk = (j >> 5) * 16 + (i >> 4);
        int lanee = ((i >> 3) & 1) * 32 + (j & 31);
        kbF[chunk * 512 + lanee * 8 + (i & 7)] = f2bf(kv);
    }
    float s = kv;
    for (int off = 32; off > 0; off >>= 1) s += __shfl_down(s, off);
    __shared__ float wsum[4];
    int lane = i & 63, w = i >> 6;
    if (lane == 0) wsum[w] = s;
    __syncthreads();
    if (i == 0) ksum[j] = wsum[0] + wsum[1] + wsum[2] + wsum[3];
}

// ---------------- der v4: acc[2][2], 8 waves, 512 blocks; xtF epilogue ----------------
// grid (256, 2): bx = 256-d-col block, by = 128-j half. 512 thr = 8 waves
// (wj = w>>2: 2, wd = w&3: 4), wave = 64j x 64d (acc[2][2] of 32x32).
// 16 i16-steps; 4 loads (4 KB) per 4 MFMAs. kbF is L2-resident (128 KB total).
__global__ __launch_bounds__(512) void der_mfma(const unsigned short* __restrict__ kbF,
                                                const unsigned short* __restrict__ XbTF,
                                                const float* __restrict__ ksum,
                                                const float* __restrict__ sig,
                                                float* __restrict__ der) {
    const int t = threadIdx.x;
    const int lane = t & 63, w = t >> 6;
    const int wj = w >> 2, wd = w & 3;
    const int bx = blockIdx.x, by = blockIdx.y;

    f32x16 acc[2][2] = {};
    const unsigned short* pA[2];
    const unsigned short* pB[2];
#pragma unroll
    for (int s = 0; s < 2; s++)
        pA[s] = &kbF[(size_t)((by * 4 + wj * 2 + s) * 16) * 512 + lane * 8];
#pragma unroll
    for (int u = 0; u < 2; u++)
        pB[u] = &XbTF[(size_t)((bx * 8 + wd * 2 + u) * 16) * 512 + lane * 8];

#pragma unroll 4
    for (int i16 = 0; i16 < 16; i16++) {
        bf16x8 a[2], b[2];
#pragma unroll
        for (int s = 0; s < 2; s++) a[s] = *(const bf16x8*)(pA[s] + i16 * 512);
#pragma unroll
        for (int u = 0; u < 2; u++) b[u] = *(const bf16x8*)(pB[u] + i16 * 512);
#pragma unroll
        for (int s = 0; s < 2; s++)
#pragma unroll
            for (int u = 0; u < 2; u++)
                acc[s][u] = __builtin_amdgcn_mfma_f32_32x32x16_bf16(a[s], b[u], acc[s][u], 0, 0, 0);
    }
    const int hl = lane >> 5, lr = lane & 31;
    const float invs2 = sig[2];
#pragma unroll
    for (int u = 0; u < 2; u++) {
        const int dcol = bx * 256 + wd * 64 + u * 32 + lr;
#pragma unroll
        for (int s = 0; s < 2; s++) {
            const int jt = by * 128 + wj * 64 + s * 32;
#pragma unroll
            for (int q = 0; q < 4; q++) {
                int jq = jt + q * 8 + 4 * hl;
                float4 ks4 = *(const float4*)&ksum[jq];
                float x0 = xtF(XbTF, dcol, jq + 0);
                float x1 = xtF(XbTF, dcol, jq + 1);
                float x2 = xtF(XbTF, dcol, jq + 2);
                float x3 = xtF(XbTF, dcol, jq + 3);
                der[(size_t)(jq + 0) * DD + dcol] = (acc[s][u][q * 4 + 0] - ks4.x * x0) * invs2;
                der[(size_t)(jq + 1) * DD + dcol] = (acc[s][u][q * 4 + 1] - ks4.y * x1) * invs2;
                der[(size_t)(jq + 2) * DD + dcol] = (acc[s][u][q * 4 + 2] - ks4.z * x2) * invs2;
                der[(size_t)(jq + 3) * DD + dcol] = (acc[s][u][q * 4 + 3] - ks4.w * x3) * invs2;
            }
        }
    }
}

// ---------------- mid-path gram (atomic version, ws < full) ----------------
__global__ __launch_bounds__(512) void gram_mfma(const unsigned short* __restrict__ XbF,
                                                 float* __restrict__ G) {
    const int t = threadIdx.x;
    const int lane = t & 63, w = t >> 6;
    const int wr = w >> 2, wc = w & 3;
    const int kc0 = blockIdx.x * 64;

    f32x16 acc[4][2] = {};
    const unsigned short* pA[4];
    const unsigned short* pB[2];
#pragma unroll
    for (int s = 0; s < 4; s++)
        pA[s] = &XbF[(size_t)((wr * 4 + s) * 4096 + kc0) * 512 + lane * 8];
#pragma unroll
    for (int u = 0; u < 2; u++)
        pB[u] = &XbF[(size_t)((wc * 2 + u) * 4096 + kc0) * 512 + lane * 8];

#pragma unroll 2
    for (int ks = 0; ks < 64; ks++) {
        bf16x8 a[4], b[2];
#pragma unroll
        for (int s = 0; s < 4; s++) a[s] = *(const bf16x8*)(pA[s] + ks * 512);
#pragma unroll
        for (int u = 0; u < 2; u++) b[u] = *(const bf16x8*)(pB[u] + ks * 512);
#pragma unroll
        for (int s = 0; s < 4; s++)
#pragma unroll
            for (int u = 0; u < 2; u++)
                acc[s][u] = __builtin_amdgcn_mfma_f32_32x32x16_bf16(a[s], b[u], acc[s][u], 0, 0, 0);
    }
    const int hl = lane >> 5, lr = lane & 31;
#pragma unroll
    for (int s = 0; s < 4; s++)
#pragma unroll
        for (int u = 0; u < 2; u++) {
            int jc = wc * 64 + u * 32 + lr;
#pragma unroll
            for (int r = 0; r < 16; r++) {
                int ir = wr * 128 + s * 32 + (r & 3) + 8 * (r >> 2) + 4 * hl;
                atomicAdd(&G[ir * NP + jc], acc[s][u][r]);
            }
        }
}

// ================= fallback fp32 path (ws too small) =================
__global__ __launch_bounds__(256) void gram_kernel(const float* __restrict__ X,
                                                   float* __restrict__ G) {
    __shared__ __align__(16) float As[32][72];
    __shared__ __align__(16) float Bs[32][72];
    const int i0 = blockIdx.x * 64;
    const int j0 = blockIdx.y * 64;
    const int k0 = blockIdx.z * 2048;
    const int t  = threadIdx.x;
    const int tx = t & 15, ty = t >> 4;
    float acc[4][4];
#pragma unroll
    for (int q = 0; q < 4; q++)
#pragma unroll
        for (int r = 0; r < 4; r++) acc[q][r] = 0.f;
    for (int kb = k0; kb < k0 + 2048; kb += 32) {
#pragma unroll
        for (int u = 0; u < 2; u++) {
            int f = t * 2 + u, row = f >> 3, c4 = (f & 7) * 4;
            float4 av = *(const float4*)&X[(size_t)(i0 + row) * DD + kb + c4];
            As[c4 + 0][row] = av.x; As[c4 + 1][row] = av.y;
            As[c4 + 2][row] = av.z; As[c4 + 3][row] = av.w;
            float4 bv = *(const float4*)&X[(size_t)(j0 + row) * DD + kb + c4];
            Bs[c4 + 0][row] = bv.x; Bs[c4 + 1][row] = bv.y;
            Bs[c4 + 2][row] = bv.z; Bs[c4 + 3][row] = bv.w;
        }
        __syncthreads();
#pragma unroll
        for (int kk = 0; kk < 32; kk++) {
            float4 a4 = *(const float4*)&As[kk][ty * 4];
            float4 b4 = *(const float4*)&Bs[kk][tx * 4];
            acc[0][0] += a4.x * b4.x; acc[0][1] += a4.x * b4.y;
            acc[0][2] += a4.x * b4.z; acc[0][3] += a4.x * b4.w;
            acc[1][0] += a4.y * b4.x; acc[1][1] += a4.y * b4.y;
            acc[1][2] += a4.y * b4.z; acc[1][3] += a4.y * b4.w;
            acc[2][0] += a4.z * b4.x; acc[2][1] += a4.z * b4.y;
            acc[2][2] += a4.z * b4.z; acc[2][3] += a4.z * b4.w;
            acc[3][0] += a4.w * b4.x; acc[3][1] += a4.w * b4.y;
            acc[3][2] += a4.w * b4.z; acc[3][3] += a4.w * b4.w;
        }
        __syncthreads();
    }
#pragma unroll
    for (int q = 0; q < 4; q++)
#pragma unroll
        for (int r = 0; r < 4; r++)
            atomicAdd(&G[(size_t)(i0 + ty * 4 + q) * NP + j0 + tx * 4 + r], acc[q][r]);
}

__global__ __launch_bounds__(256) void der_kernel(const float* __restrict__ X,
                                                  const float* __restrict__ kmat,
                                                  const float* __restrict__ ksum,
                                                  const float* __restrict__ sig,
                                                  float* __restrict__ der) {
    const int j0 = blockIdx.y * 32;
    const int d0 = blockIdx.x * 512 + threadIdx.x * 2;
    const float invs2 = sig[2];
    float2 acc[32];
#pragma unroll
    for (int jl = 0; jl < 32; jl++) { acc[jl].x = 0.f; acc[jl].y = 0.f; }
    for (int i = 0; i < NP; i++) {
        float2 xv = *(const float2*)&X[(size_t)i * DD + d0];
        const float4* kr = (const float4*)&kmat[i * NP + j0];
#pragma unroll
        for (int q = 0; q < 8; q++) {
            float4 k4 = kr[q];
            acc[q * 4 + 0].x += k4.x * xv.x; acc[q * 4 + 0].y += k4.x * xv.y;
            acc[q * 4 + 1].x += k4.y * xv.x; acc[q * 4 + 1].y += k4.y * xv.y;
            acc[q * 4 + 2].x += k4.z * xv.x; acc[q * 4 + 2].y += k4.z * xv.y;
            acc[q * 4 + 3].x += k4.w * xv.x; acc[q * 4 + 3].y += k4.w * xv.y;
        }
    }
#pragma unroll
    for (int jl = 0; jl < 32; jl++) {
        int j = j0 + jl;
        float2 xj = *(const float2*)&X[(size_t)j * DD + d0];
        float ks = ksum[j];
        float2 o;
        o.x = (acc[jl].x - ks * xj.x) * invs2;
        o.y = (acc[jl].y - ks * xj.y) * invs2;
        *(float2*)&der[(size_t)j * DD + d0] = o;
    }
}

extern "C" void kernel_launch(void* const* d_in, const int* in_sizes, int n_in,
                              void* d_out, int out_size, void* d_ws, size_t ws_size,
                              hipStream_t stream) {
    const float* X   = (const float*)d_in[0];
    const float* EMA = (const float*)d_in[1];
    float* out = (float*)d_out;
    float* ws  = (float*)d_ws;

    float* G    = ws;
    float* sq   = ws + WS_SQ;
    float* ksum = ws + WS_KSUM;
    float* sig  = ws + WS_SIG;

    float* kout      = out;
    float* der       = out + NP * NP;
    float* sigma_out = out + out_size - 1;

    if (ws_size >= (size_t)WS_NEED_MID) {
        unsigned short* XbF  = (unsigned short*)((char*)d_ws + XBF_BYTE_OFF);
        unsigned short* XbTF = (unsigned short*)((char*)d_ws + XBTF_BYTE_OFF);
        unsigned short* kbF  = (unsigned short*)((char*)d_ws + KBF_BYTE_OFF);

        cast_kernel<<<dim3(1024, 4), 256, 0, stream>>>(X, XbF, XbTF);
        if (ws_size >= (size_t)WS_NEED_FULL) {
            float* P = (float*)((char*)d_ws + PART_BYTE_OFF);
            gram_mfma_part<<<dim3(2, 2, 64), 256, 0, stream>>>(XbF, P);
            gram_reduce<<<64, 256, 0, stream>>>(P, G);
        } else {
            hipMemsetAsync(G, 0, (size_t)NP * NP * sizeof(float), stream);
            gram_mfma<<<64, 512, 0, stream>>>(XbF, G);
        }
        median_sigma_kernel<<<1, 1024, 0, stream>>>(G, EMA, sq, sig, sigma_out);
        kexp_kernel<<<NP, NP, 0, stream>>>(G, sq, sig, kout, kbF, ksum);
        der_mfma<<<dim3(256, 2), 512, 0, stream>>>(kbF, XbTF, ksum, sig, der);
    } else {
        hipMemsetAsync(G, 0, (size_t)NP * NP * sizeof(float), stream);
        gram_kernel<<<dim3(4, 4, 32), 256, 0, stream>>>(X, G);
        median_sigma_kernel<<<1, 1024, 0, stream>>>(G, EMA, sq, sig, sigma_out);
        kexp_kernel<<<NP, NP, 0, stream>>>(G, sq, sig, kout, nullptr, ksum);
        der_kernel<<<dim3(128, 8), 256, 0, stream>>>(X, kout, ksum, sig, der);
    }
}